// Round 13
// baseline (110.958 us; speedup 1.0000x reference)
//
#include <hip/hip_runtime.h>

#define ALPHA 0.2f
constexpr int N = 50000;
constexpr int E = 800000;

typedef __attribute__((ext_vector_type(8))) short bf16x8;
typedef __attribute__((ext_vector_type(4))) float f32x4;

__device__ inline ushort f2bf(float v) {
  uint u = __float_as_uint(v);
  return (ushort)((u + 0x7fff + ((u >> 16) & 1)) >> 16);  // RNE, finite inputs
}
__device__ inline float bf2f(ushort u) { return __uint_as_float(((uint)u) << 16); }

constexpr int LDX = 136;  // LDS row stride in bf16: 272 B -> 4-bank/row rotation, 16B-aligned

constexpr int BN   = 128;                       // nodes per bucket
constexpr int NB   = (N + BN - 1) / BN;         // 391 buckets
constexpr int NBP  = 512;                       // padded for scans
constexpr int PSTR = 392;                       // partial row stride (ints)
constexpr int CHUNK = 8192;                     // edges per part/bhist block
constexpr int NBLK  = (E + CHUNK - 1) / CHUNK;  // 98
constexpr int FROWS = 32;                       // feat tile rows
constexpr int FEATB = (N + FROWS - 1) / FROWS;  // 1563 feat blocks
constexpr int SMEMB = 2 * FROWS * LDX * 2;      // 17408 B dynamic LDS
constexpr int NBIN  = 8;                        // src bins (src>>13: 0..6), pow2 pad
constexpr int NKEY  = BN * NBIN;                // 1024 (node-local, bin) keys

// -------------------- K1: bhist partials (blocks 0..97) + weight prep (98..113) ------
// frag slot f = (ks*8 + jb)*64 + l holds W[jb*16 + (l&15)][ks*32 + (l>>4)*8 + 0..7]
__global__ __launch_bounds__(256) void k1_kernel(const float* __restrict__ W1,
    const float* __restrict__ W2, ushort* __restrict__ wf1hi, ushort* __restrict__ wf1lo,
    ushort* __restrict__ wf2hi, ushort* __restrict__ wf2lo,
    const int* __restrict__ dst, int* __restrict__ partial) {
  const int bid = blockIdx.x;
  const int t = threadIdx.x;
  if (bid < NBLK) {
    __shared__ int lh[NB];
    const int e0 = bid * CHUNK, e1 = min(e0 + CHUNK, E);
    for (int i = t; i < NB; i += 256) lh[i] = 0;
    __syncthreads();
    for (int i = e0 + t; i < e1; i += 256)
      atomicAdd(&lh[((unsigned)dst[i]) >> 7], 1);
    __syncthreads();
    for (int i = t; i < NB; i += 256) partial[bid * PSTR + i] = lh[i];
    return;
  }
  int g = (bid - NBLK) * 256 + t;          // 0..4095
  const float* W = (g < 2048) ? W1 : W2;
  ushort* whi = (g < 2048) ? wf1hi : wf2hi;
  ushort* wlo = (g < 2048) ? wf1lo : wf2lo;
  int f = g & 2047;
  int ks = f >> 9, rem = f & 511, jb = rem >> 6, l = rem & 63;
  int m = jb * 16 + (l & 15), kb = ks * 32 + (l >> 4) * 8;
#pragma unroll
  for (int q = 0; q < 2; ++q) {
    float4 v = *(const float4*)&W[m * 128 + kb + q * 4];
    ushort4 hi, lo;
    hi.x = f2bf(v.x); lo.x = f2bf(v.x - bf2f(hi.x));
    hi.y = f2bf(v.y); lo.y = f2bf(v.y - bf2f(hi.y));
    hi.z = f2bf(v.z); lo.z = f2bf(v.z - bf2f(hi.z));
    hi.w = f2bf(v.w); lo.w = f2bf(v.w - bf2f(hi.w));
    *(ushort4*)&whi[f * 8 + q * 4] = hi;
    *(ushort4*)&wlo[f * 8 + q * 4] = lo;
  }
}

// -------------------- K2: column-sum + scan -> bucket_base, chunk_base ---------------
__global__ __launch_bounds__(NBP) void colscan_kernel(const int* __restrict__ partial,
    int* __restrict__ bucket_base, int* __restrict__ chunk_base) {
  __shared__ int sh[NBP];
  const int t = threadIdx.x;
  int tot = 0;
  if (t < NB) {
#pragma unroll 4
    for (int blk = 0; blk < NBLK; ++blk) tot += partial[blk * PSTR + t];
  }
  sh[t] = (t < NB) ? tot : 0;
  __syncthreads();
  for (int off = 1; off < NBP; off <<= 1) {
    int u = (t >= off) ? sh[t - off] : 0;
    __syncthreads();
    sh[t] += u;
    __syncthreads();
  }
  if (t < NB) {
    int base = sh[t] - tot;  // exclusive
    bucket_base[t] = base;
    int run = base;
#pragma unroll 4
    for (int blk = 0; blk < NBLK; ++blk) {
      chunk_base[blk * PSTR + t] = run;
      run += partial[blk * PSTR + t];
    }
  }
  if (t == NB - 1) bucket_base[NB] = sh[t];  // = E
}

// -------------------- K3: part (blocks 0..97) UNION feat (blocks 98..1660) -----------
__global__ __launch_bounds__(256, 6) void featpart_kernel(
    const float* __restrict__ x,
    const ushort* __restrict__ wf1hi, const ushort* __restrict__ wf1lo,
    const ushort* __restrict__ wf2hi, const ushort* __restrict__ wf2lo,
    const float* __restrict__ attn_l, const float* __restrict__ attn_r,
    ushort* __restrict__ ft_bf, float* __restrict__ a1, float* __restrict__ a2,
    const int* __restrict__ src, const int* __restrict__ dst,
    const int* __restrict__ chunk_base, int* __restrict__ ebuf) {
  extern __shared__ char smem[];
  const int bid = blockIdx.x;
  const int tid = threadIdx.x;

  if (bid < NBLK) {
    // ==== part: direct placement at precomputed per-(chunk,bucket) bases (no sort) ====
    int* curs = (int*)smem;          // [NB]
    const int e0 = bid * CHUNK, e1 = min(e0 + CHUNK, E);
    for (int k = tid; k < NB; k += 256) curs[k] = chunk_base[bid * PSTR + k];
    __syncthreads();
    for (int i = e0 + tid; i < e1; i += 256) {
      int s = src[i], d = dst[i];
      int pos = atomicAdd(&curs[((unsigned)d) >> 7], 1);
      ebuf[pos] = (s << 7) | (d & 127);
    }
    return;
  }

  // ======== feat: ft = lrelu(x@W1^T)@W2^T (bf16 hi/lo MFMA), a1/a2 reductions ========
  ushort* sXhi = (ushort*)smem;        // [FROWS][LDX]
  ushort* sXlo = sXhi + FROWS * LDX;
  const int w = tid >> 6, l = tid & 63;
  const int lr = l & 15, lg4 = l >> 4;
  const int rowBase = (bid - NBLK) * FROWS;

  for (int i = tid; i < FROWS * 32; i += 256) {
    int row = i >> 5, kc = i & 31;
    int g = rowBase + row;
    float4 v = make_float4(0.f, 0.f, 0.f, 0.f);
    if (g < N) v = reinterpret_cast<const float4*>(x)[g * 32 + kc];
    ushort4 hi, lo;
    hi.x = f2bf(v.x); lo.x = f2bf(v.x - bf2f(hi.x));
    hi.y = f2bf(v.y); lo.y = f2bf(v.y - bf2f(hi.y));
    hi.z = f2bf(v.z); lo.z = f2bf(v.z - bf2f(hi.z));
    hi.w = f2bf(v.w); lo.w = f2bf(v.w - bf2f(hi.w));
    *(ushort4*)&sXhi[row * LDX + kc * 4] = hi;
    *(ushort4*)&sXlo[row * LDX + kc * 4] = lo;
  }
  __syncthreads();

  f32x4 acc[2][2];
#pragma unroll
  for (int mi = 0; mi < 2; ++mi)
#pragma unroll
    for (int jj = 0; jj < 2; ++jj) acc[mi][jj] = (f32x4){0.f, 0.f, 0.f, 0.f};

  // ---- stage 1: h1 = x @ W1^T (B-frags streamed per ks from L2) ----
#pragma unroll
  for (int ks = 0; ks < 4; ++ks) {
    bf16x8 bh[2], bl[2], ah[2], al[2];
#pragma unroll
    for (int jj = 0; jj < 2; ++jj) {
      int off = ((ks * 8 + (2 * w + jj)) * 64 + l) * 8;
      bh[jj] = *(const bf16x8*)&wf1hi[off];
      bl[jj] = *(const bf16x8*)&wf1lo[off];
    }
#pragma unroll
    for (int mi = 0; mi < 2; ++mi) {
      int addr = (mi * 16 + lr) * LDX + ks * 32 + lg4 * 8;
      ah[mi] = *(const bf16x8*)&sXhi[addr];
      al[mi] = *(const bf16x8*)&sXlo[addr];
    }
#pragma unroll
    for (int mi = 0; mi < 2; ++mi)
#pragma unroll
      for (int jj = 0; jj < 2; ++jj) {
        acc[mi][jj] = __builtin_amdgcn_mfma_f32_16x16x32_bf16(ah[mi], bh[jj], acc[mi][jj], 0, 0, 0);
        acc[mi][jj] = __builtin_amdgcn_mfma_f32_16x16x32_bf16(ah[mi], bl[jj], acc[mi][jj], 0, 0, 0);
        acc[mi][jj] = __builtin_amdgcn_mfma_f32_16x16x32_bf16(al[mi], bh[jj], acc[mi][jj], 0, 0, 0);
      }
  }
  __syncthreads();  // all stage-1 LDS reads done before overwrite

  // write h2 = lrelu(h1) back to sX (hi/lo); D layout: row=4*(l>>4)+r, col=l&15
#pragma unroll
  for (int mi = 0; mi < 2; ++mi)
#pragma unroll
    for (int jj = 0; jj < 2; ++jj)
#pragma unroll
      for (int r = 0; r < 4; ++r) {
        float v = acc[mi][jj][r];
        v = v > 0.f ? v : ALPHA * v;
        int row = mi * 16 + lg4 * 4 + r;
        int col = w * 32 + jj * 16 + lr;
        ushort hv = f2bf(v);
        sXhi[row * LDX + col] = hv;
        sXlo[row * LDX + col] = f2bf(v - bf2f(hv));
      }
  __syncthreads();

#pragma unroll
  for (int mi = 0; mi < 2; ++mi)
#pragma unroll
    for (int jj = 0; jj < 2; ++jj) acc[mi][jj] = (f32x4){0.f, 0.f, 0.f, 0.f};

  // ---- stage 2: ft = h2 @ W2^T ----
#pragma unroll
  for (int ks = 0; ks < 4; ++ks) {
    bf16x8 bh[2], bl[2], ah[2], al[2];
#pragma unroll
    for (int jj = 0; jj < 2; ++jj) {
      int off = ((ks * 8 + (2 * w + jj)) * 64 + l) * 8;
      bh[jj] = *(const bf16x8*)&wf2hi[off];
      bl[jj] = *(const bf16x8*)&wf2lo[off];
    }
#pragma unroll
    for (int mi = 0; mi < 2; ++mi) {
      int addr = (mi * 16 + lr) * LDX + ks * 32 + lg4 * 8;
      ah[mi] = *(const bf16x8*)&sXhi[addr];
      al[mi] = *(const bf16x8*)&sXlo[addr];
    }
#pragma unroll
    for (int mi = 0; mi < 2; ++mi)
#pragma unroll
      for (int jj = 0; jj < 2; ++jj) {
        acc[mi][jj] = __builtin_amdgcn_mfma_f32_16x16x32_bf16(ah[mi], bh[jj], acc[mi][jj], 0, 0, 0);
        acc[mi][jj] = __builtin_amdgcn_mfma_f32_16x16x32_bf16(ah[mi], bl[jj], acc[mi][jj], 0, 0, 0);
        acc[mi][jj] = __builtin_amdgcn_mfma_f32_16x16x32_bf16(al[mi], bh[jj], acc[mi][jj], 0, 0, 0);
      }
  }

  // ---- epilogue: ft (bf16) + a1/a2 via 16-lane shuffle reduce over d ----
#pragma unroll
  for (int mi = 0; mi < 2; ++mi)
#pragma unroll
    for (int jj = 0; jj < 2; ++jj) {
      int h = 2 * w + jj;
      float alv = attn_l[h * 16 + lr], arv = attn_r[h * 16 + lr];
#pragma unroll
      for (int r = 0; r < 4; ++r) {
        float v = acc[mi][jj][r];
        int grow = rowBase + mi * 16 + lg4 * 4 + r;
        bool valid = grow < N;
        if (valid) ft_bf[grow * 128 + h * 16 + lr] = f2bf(v);
        float sl = v * alv, sr = v * arv;
#pragma unroll
        for (int off = 8; off; off >>= 1) {
          sl += __shfl_xor(sl, off, 16);
          sr += __shfl_xor(sr, off, 16);
        }
        if (valid && lr == 0) { a1[grow * 8 + h] = sl; a2[grow * 8 + h] = sr; }
      }
    }
}

// ---- K4: per-bucket counting sort keyed by (node-local, src-bin) + CSR build --------
// Within each node's edge list, edges are ordered by src>>13 (7 live bins of ~2MB ft
// slice each, L2-resident). agg walks lists front-to-back -> the global gather window
// sweeps ft bin-by-bin, raising L2 hit rate. Order within a node is math-free (no
// max-subtraction; partial sums add).
__global__ __launch_bounds__(256) void fine_kernel(const int* __restrict__ ebuf,
    const int* __restrict__ bucket_base, int* __restrict__ row_ptr,
    int* __restrict__ col_src) {
  __shared__ int ldeg[NKEY], sA[NKEY], sB[NKEY], curs[NKEY];
  const int b = blockIdx.x, t = threadIdx.x;
  const int node0 = b * BN;
  const int nloc = min(BN, N - node0);
  const int bstart = bucket_base[b], bend = bucket_base[b + 1];
  for (int k = t; k < NKEY; k += 256) ldeg[k] = 0;
  __syncthreads();
  for (int i = bstart + t; i < bend; i += 256) {
    int pr = ebuf[i];
    int key = ((pr & 127) << 3) | ((pr >> 7) >> 13);
    atomicAdd(&ldeg[key], 1);
  }
  __syncthreads();
  for (int k = t; k < NKEY; k += 256) sA[k] = ldeg[k];
  __syncthreads();
  int* pin = sA; int* pout = sB;
  for (int off = 1; off < NKEY; off <<= 1) {
    for (int k = t; k < NKEY; k += 256)
      pout[k] = pin[k] + ((k >= off) ? pin[k - off] : 0);
    __syncthreads();
    int* tmp = pin; pin = pout; pout = tmp;
  }
  for (int k = t; k < NKEY; k += 256) curs[k] = bstart + pin[k] - ldeg[k];  // exclusive
  __syncthreads();
  if (t < nloc) row_ptr[node0 + t] = curs[t * NBIN];
  if (b == NB - 1 && t == 0) row_ptr[N] = bend;
  for (int i = bstart + t; i < bend; i += 256) {
    int pr = ebuf[i];
    int key = ((pr & 127) << 3) | ((pr >> 7) >> 13);
    int pos = atomicAdd(&curs[key], 1);
    col_src[pos] = pr >> 7;
  }
}

// -------------------- K5: single-pass softmax-aggregate (round-8 proven form) --------
// 64-lane group per node. Phase A: lane t=(edge e=t>>3, head hA=t&7) computes each
// (e,h) logit/exp exactly ONCE. Phase B: broadcast p and src via shfl; lane t
// accumulates d-pair t*2 (head hB=t>>3). 8 gathers in flight.
__global__ __launch_bounds__(256) void agg_kernel(const int* __restrict__ row_ptr,
    const int* __restrict__ col_src, const ushort* __restrict__ ft_bf,
    const float* __restrict__ a1, const float* __restrict__ a2,
    float* __restrict__ out) {
  const int node = blockIdx.x * 4 + (threadIdx.x >> 6);
  if (node >= N) return;
  const int t = threadIdx.x & 63;
  const int eSlot = t >> 3;
  const int hA = t & 7;
  const int hB = t >> 3;
  const int start = row_ptr[node], end = row_ptr[node + 1];
  const float a2nA = a2[node * 8 + hA];

  float l = 0.f, acc0 = 0.f, acc1 = 0.f;
  for (int base = start; base < end; base += 8) {
    int rem = end - base; rem = rem > 8 ? 8 : rem;
    int idx = base + (eSlot < rem ? eSlot : rem - 1);
    int s = col_src[idx];
    float lg = a1[s * 8 + hA] + a2nA;
    lg = lg > 0.f ? lg : ALPHA * lg;
    float p = (eSlot < rem) ? __expf(lg) : 0.f;
#pragma unroll
    for (int e = 0; e < 8; ++e) {
      float pe = __shfl(p, e * 8 + hB);
      int se = __shfl(s, e * 8);
      ushort2 f = *(const ushort2*)&ft_bf[se * 128 + t * 2];
      l += pe;
      acc0 = fmaf(pe, bf2f(f.x), acc0);
      acc1 = fmaf(pe, bf2f(f.y), acc1);
    }
  }
  float inv = (end > start) ? 1.f / l : 0.f;
  *(float2*)&out[node * 128 + t * 2] = make_float2(acc0 * inv, acc1 * inv);
}

// -------------------- launch --------------------
extern "C" void kernel_launch(void* const* d_in, const int* in_sizes, int n_in,
                              void* d_out, int out_size, void* d_ws, size_t ws_size,
                              hipStream_t stream) {
  const float* x      = (const float*)d_in[0];
  const float* W1     = (const float*)d_in[1];
  const float* W2     = (const float*)d_in[2];
  const float* attn_l = (const float*)d_in[3];
  const float* attn_r = (const float*)d_in[4];
  const int*   edge   = (const int*)d_in[5];
  const int*   src    = edge;
  const int*   dst    = edge + E;
  float* out = (float*)d_out;

  char* ws = (char*)d_ws;
  ushort* ft_bf       = (ushort*)(ws);                 // 12,800,000 B
  float*  a1          = (float*) (ws + 12800000);      //  1,600,000 B
  float*  a2          = (float*) (ws + 14400000);      //  1,600,000 B
  int*    row_ptr     = (int*)   (ws + 16000000);      //    200,064 B (N+1 ints)
  int*    bucket_base = (int*)   (ws + 16200064);      //      1,600 B (392 ints)
  int*    col_src     = (int*)   (ws + 16201664);      //  3,200,000 B
  ushort* wf1hi       = (ushort*)(ws + 19401664);      //     32,768 B each
  ushort* wf1lo       = (ushort*)(ws + 19434432);
  ushort* wf2hi       = (ushort*)(ws + 19467200);
  ushort* wf2lo       = (ushort*)(ws + 19499968);
  int*    ebuf        = (int*)   (ws + 19532736);      //  3,200,000 B
  int*    partial     = (int*)   (ws + 22732736);      //    153,664 B (98x392 ints)
  int*    chunk_base  = (int*)   (ws + 22886400);      //    153,664 B -> end ~23.04 MB

  k1_kernel<<<NBLK + 16, 256, 0, stream>>>(W1, W2, wf1hi, wf1lo, wf2hi, wf2lo, dst, partial);
  colscan_kernel<<<1, NBP, 0, stream>>>(partial, bucket_base, chunk_base);
  featpart_kernel<<<NBLK + FEATB, 256, SMEMB, stream>>>(
      x, wf1hi, wf1lo, wf2hi, wf2lo, attn_l, attn_r, ft_bf, a1, a2,
      src, dst, chunk_base, ebuf);
  fine_kernel<<<NB, 256, 0, stream>>>(ebuf, bucket_base, row_ptr, col_src);
  agg_kernel<<<(N + 3) / 4, 256, 0, stream>>>(row_ptr, col_src, ft_bf, a1, a2, out);
}

// Round 14
// 109.757 us; speedup vs baseline: 1.0109x; 1.0109x over previous
//
#include <hip/hip_runtime.h>

#define ALPHA 0.2f
constexpr int N = 50000;
constexpr int E = 800000;

typedef __attribute__((ext_vector_type(8))) short bf16x8;
typedef __attribute__((ext_vector_type(4))) float f32x4;

__device__ inline ushort f2bf(float v) {
  uint u = __float_as_uint(v);
  return (ushort)((u + 0x7fff + ((u >> 16) & 1)) >> 16);  // RNE, finite inputs
}
__device__ inline float bf2f(ushort u) { return __uint_as_float(((uint)u) << 16); }

constexpr int LDX = 136;  // LDS row stride in bf16: 272 B -> 4-bank/row rotation, 16B-aligned

constexpr int BN   = 128;                       // nodes per bucket
constexpr int NB   = (N + BN - 1) / BN;         // 391 buckets
constexpr int NBP  = 512;                       // padded for scans
constexpr int PSTR = 392;                       // partial row stride (ints)
constexpr int CHUNK = 4096;                     // edges per part/bhist block
constexpr int NBLK  = (E + CHUNK - 1) / CHUNK;  // 196
constexpr int FROWS = 32;                       // feat tile rows
constexpr int FEATB = (N + FROWS - 1) / FROWS;  // 1563 feat blocks
constexpr int SMEMB = 2 * FROWS * LDX * 2;      // 17408 B dynamic LDS

// -------------------- K1: bhist partials (blocks 0..195) + weight prep (196..211) ----
// frag slot f = (ks*8 + jb)*64 + l holds W[jb*16 + (l&15)][ks*32 + (l>>4)*8 + 0..7]
__global__ __launch_bounds__(256) void k1_kernel(const float* __restrict__ W1,
    const float* __restrict__ W2, ushort* __restrict__ wf1hi, ushort* __restrict__ wf1lo,
    ushort* __restrict__ wf2hi, ushort* __restrict__ wf2lo,
    const int* __restrict__ dst, int* __restrict__ partial) {
  const int bid = blockIdx.x;
  const int t = threadIdx.x;
  if (bid < NBLK) {
    __shared__ int lh[NB];
    const int e0 = bid * CHUNK, e1 = min(e0 + CHUNK, E);
    for (int i = t; i < NB; i += 256) lh[i] = 0;
    __syncthreads();
    for (int i = e0 + t; i < e1; i += 256)
      atomicAdd(&lh[((unsigned)dst[i]) >> 7], 1);
    __syncthreads();
    for (int i = t; i < NB; i += 256) partial[bid * PSTR + i] = lh[i];
    return;
  }
  int g = (bid - NBLK) * 256 + t;          // 0..4095
  const float* W = (g < 2048) ? W1 : W2;
  ushort* whi = (g < 2048) ? wf1hi : wf2hi;
  ushort* wlo = (g < 2048) ? wf1lo : wf2lo;
  int f = g & 2047;
  int ks = f >> 9, rem = f & 511, jb = rem >> 6, l = rem & 63;
  int m = jb * 16 + (l & 15), kb = ks * 32 + (l >> 4) * 8;
#pragma unroll
  for (int q = 0; q < 2; ++q) {
    float4 v = *(const float4*)&W[m * 128 + kb + q * 4];
    ushort4 hi, lo;
    hi.x = f2bf(v.x); lo.x = f2bf(v.x - bf2f(hi.x));
    hi.y = f2bf(v.y); lo.y = f2bf(v.y - bf2f(hi.y));
    hi.z = f2bf(v.z); lo.z = f2bf(v.z - bf2f(hi.z));
    hi.w = f2bf(v.w); lo.w = f2bf(v.w - bf2f(hi.w));
    *(ushort4*)&whi[f * 8 + q * 4] = hi;
    *(ushort4*)&wlo[f * 8 + q * 4] = lo;
  }
}

// -------------------- K2: column-sum + scan -> bucket_base, chunk_base ---------------
__global__ __launch_bounds__(NBP) void colscan_kernel(const int* __restrict__ partial,
    int* __restrict__ bucket_base, int* __restrict__ chunk_base) {
  __shared__ int sh[NBP];
  const int t = threadIdx.x;
  int tot = 0;
  if (t < NB) {
#pragma unroll 4
    for (int blk = 0; blk < NBLK; ++blk) tot += partial[blk * PSTR + t];
  }
  sh[t] = (t < NB) ? tot : 0;
  __syncthreads();
  for (int off = 1; off < NBP; off <<= 1) {
    int u = (t >= off) ? sh[t - off] : 0;
    __syncthreads();
    sh[t] += u;
    __syncthreads();
  }
  if (t < NB) {
    int base = sh[t] - tot;  // exclusive
    bucket_base[t] = base;
    int run = base;
#pragma unroll 4
    for (int blk = 0; blk < NBLK; ++blk) {
      chunk_base[blk * PSTR + t] = run;
      run += partial[blk * PSTR + t];
    }
  }
  if (t == NB - 1) bucket_base[NB] = sh[t];  // = E
}

// -------------------- K3: part (blocks 0..195) UNION feat (blocks 196..1758) ---------
__global__ __launch_bounds__(256, 6) void featpart_kernel(
    const float* __restrict__ x,
    const ushort* __restrict__ wf1hi, const ushort* __restrict__ wf1lo,
    const ushort* __restrict__ wf2hi, const ushort* __restrict__ wf2lo,
    const float* __restrict__ attn_l, const float* __restrict__ attn_r,
    ushort* __restrict__ ft_bf, float* __restrict__ a1, float* __restrict__ a2,
    const int* __restrict__ src, const int* __restrict__ dst,
    const int* __restrict__ chunk_base, int* __restrict__ ebuf) {
  extern __shared__ char smem[];
  const int bid = blockIdx.x;
  const int tid = threadIdx.x;

  if (bid < NBLK) {
    // ==== part: direct placement at precomputed per-(chunk,bucket) bases (no sort) ====
    int* curs = (int*)smem;          // [NB]
    const int e0 = bid * CHUNK, e1 = min(e0 + CHUNK, E);
    for (int k = tid; k < NB; k += 256) curs[k] = chunk_base[bid * PSTR + k];
    __syncthreads();
    for (int i = e0 + tid; i < e1; i += 256) {
      int s = src[i], d = dst[i];
      int pos = atomicAdd(&curs[((unsigned)d) >> 7], 1);
      ebuf[pos] = (s << 7) | (d & 127);
    }
    return;
  }

  // ======== feat: ft = lrelu(x@W1^T)@W2^T (bf16 hi/lo MFMA), a1/a2 reductions ========
  ushort* sXhi = (ushort*)smem;        // [FROWS][LDX]
  ushort* sXlo = sXhi + FROWS * LDX;
  const int w = tid >> 6, l = tid & 63;
  const int lr = l & 15, lg4 = l >> 4;
  const int rowBase = (bid - NBLK) * FROWS;

  for (int i = tid; i < FROWS * 32; i += 256) {
    int row = i >> 5, kc = i & 31;
    int g = rowBase + row;
    float4 v = make_float4(0.f, 0.f, 0.f, 0.f);
    if (g < N) v = reinterpret_cast<const float4*>(x)[g * 32 + kc];
    ushort4 hi, lo;
    hi.x = f2bf(v.x); lo.x = f2bf(v.x - bf2f(hi.x));
    hi.y = f2bf(v.y); lo.y = f2bf(v.y - bf2f(hi.y));
    hi.z = f2bf(v.z); lo.z = f2bf(v.z - bf2f(hi.z));
    hi.w = f2bf(v.w); lo.w = f2bf(v.w - bf2f(hi.w));
    *(ushort4*)&sXhi[row * LDX + kc * 4] = hi;
    *(ushort4*)&sXlo[row * LDX + kc * 4] = lo;
  }
  __syncthreads();

  f32x4 acc[2][2];
#pragma unroll
  for (int mi = 0; mi < 2; ++mi)
#pragma unroll
    for (int jj = 0; jj < 2; ++jj) acc[mi][jj] = (f32x4){0.f, 0.f, 0.f, 0.f};

  // ---- stage 1: h1 = x @ W1^T (B-frags streamed per ks from L2) ----
#pragma unroll
  for (int ks = 0; ks < 4; ++ks) {
    bf16x8 bh[2], bl[2], ah[2], al[2];
#pragma unroll
    for (int jj = 0; jj < 2; ++jj) {
      int off = ((ks * 8 + (2 * w + jj)) * 64 + l) * 8;
      bh[jj] = *(const bf16x8*)&wf1hi[off];
      bl[jj] = *(const bf16x8*)&wf1lo[off];
    }
#pragma unroll
    for (int mi = 0; mi < 2; ++mi) {
      int addr = (mi * 16 + lr) * LDX + ks * 32 + lg4 * 8;
      ah[mi] = *(const bf16x8*)&sXhi[addr];
      al[mi] = *(const bf16x8*)&sXlo[addr];
    }
#pragma unroll
    for (int mi = 0; mi < 2; ++mi)
#pragma unroll
      for (int jj = 0; jj < 2; ++jj) {
        acc[mi][jj] = __builtin_amdgcn_mfma_f32_16x16x32_bf16(ah[mi], bh[jj], acc[mi][jj], 0, 0, 0);
        acc[mi][jj] = __builtin_amdgcn_mfma_f32_16x16x32_bf16(ah[mi], bl[jj], acc[mi][jj], 0, 0, 0);
        acc[mi][jj] = __builtin_amdgcn_mfma_f32_16x16x32_bf16(al[mi], bh[jj], acc[mi][jj], 0, 0, 0);
      }
  }
  __syncthreads();  // all stage-1 LDS reads done before overwrite

  // write h2 = lrelu(h1) back to sX (hi/lo); D layout: row=4*(l>>4)+r, col=l&15
#pragma unroll
  for (int mi = 0; mi < 2; ++mi)
#pragma unroll
    for (int jj = 0; jj < 2; ++jj)
#pragma unroll
      for (int r = 0; r < 4; ++r) {
        float v = acc[mi][jj][r];
        v = v > 0.f ? v : ALPHA * v;
        int row = mi * 16 + lg4 * 4 + r;
        int col = w * 32 + jj * 16 + lr;
        ushort hv = f2bf(v);
        sXhi[row * LDX + col] = hv;
        sXlo[row * LDX + col] = f2bf(v - bf2f(hv));
      }
  __syncthreads();

#pragma unroll
  for (int mi = 0; mi < 2; ++mi)
#pragma unroll
    for (int jj = 0; jj < 2; ++jj) acc[mi][jj] = (f32x4){0.f, 0.f, 0.f, 0.f};

  // ---- stage 2: ft = h2 @ W2^T ----
#pragma unroll
  for (int ks = 0; ks < 4; ++ks) {
    bf16x8 bh[2], bl[2], ah[2], al[2];
#pragma unroll
    for (int jj = 0; jj < 2; ++jj) {
      int off = ((ks * 8 + (2 * w + jj)) * 64 + l) * 8;
      bh[jj] = *(const bf16x8*)&wf2hi[off];
      bl[jj] = *(const bf16x8*)&wf2lo[off];
    }
#pragma unroll
    for (int mi = 0; mi < 2; ++mi) {
      int addr = (mi * 16 + lr) * LDX + ks * 32 + lg4 * 8;
      ah[mi] = *(const bf16x8*)&sXhi[addr];
      al[mi] = *(const bf16x8*)&sXlo[addr];
    }
#pragma unroll
    for (int mi = 0; mi < 2; ++mi)
#pragma unroll
      for (int jj = 0; jj < 2; ++jj) {
        acc[mi][jj] = __builtin_amdgcn_mfma_f32_16x16x32_bf16(ah[mi], bh[jj], acc[mi][jj], 0, 0, 0);
        acc[mi][jj] = __builtin_amdgcn_mfma_f32_16x16x32_bf16(ah[mi], bl[jj], acc[mi][jj], 0, 0, 0);
        acc[mi][jj] = __builtin_amdgcn_mfma_f32_16x16x32_bf16(al[mi], bh[jj], acc[mi][jj], 0, 0, 0);
      }
  }

  // ---- epilogue: ft (bf16) + a1/a2 via 16-lane shuffle reduce over d ----
#pragma unroll
  for (int mi = 0; mi < 2; ++mi)
#pragma unroll
    for (int jj = 0; jj < 2; ++jj) {
      int h = 2 * w + jj;
      float alv = attn_l[h * 16 + lr], arv = attn_r[h * 16 + lr];
#pragma unroll
      for (int r = 0; r < 4; ++r) {
        float v = acc[mi][jj][r];
        int grow = rowBase + mi * 16 + lg4 * 4 + r;
        bool valid = grow < N;
        if (valid) ft_bf[grow * 128 + h * 16 + lr] = f2bf(v);
        float sl = v * alv, sr = v * arv;
#pragma unroll
        for (int off = 8; off; off >>= 1) {
          sl += __shfl_xor(sl, off, 16);
          sr += __shfl_xor(sr, off, 16);
        }
        if (valid && lr == 0) { a1[grow * 8 + h] = sl; a2[grow * 8 + h] = sr; }
      }
    }
}

// ---- K4: per-bucket fine sort + local CSR build (wave shfl-scan, 3 barriers) --------
__global__ __launch_bounds__(256) void fine_kernel(const int* __restrict__ ebuf,
    const int* __restrict__ bucket_base, int* __restrict__ row_ptr,
    int* __restrict__ col_src) {
  __shared__ int ldeg[BN], curs[BN];
  __shared__ int w0tot;
  const int b = blockIdx.x, t = threadIdx.x;
  const int node0 = b * BN;
  const int nloc = min(BN, N - node0);
  const int bstart = bucket_base[b], bend = bucket_base[b + 1];
  if (t < BN) ldeg[t] = 0;
  __syncthreads();
  for (int i = bstart + t; i < bend; i += 256)
    atomicAdd(&ldeg[ebuf[i] & 127], 1);
  __syncthreads();
  // 128-wide exclusive scan: per-wave shfl_up inclusive scan + wave-0 total handoff
  int v = (t < BN) ? ldeg[t] : 0;
  int sc = v;
#pragma unroll
  for (int off = 1; off < 64; off <<= 1) {
    int u = __shfl_up(sc, off, 64);
    if ((t & 63) >= off) sc += u;
  }
  if (t == 63) w0tot = sc;
  __syncthreads();
  int excl = sc - v + ((t >= 64 && t < BN) ? w0tot : 0);
  if (t < nloc) {
    int base = bstart + excl;
    row_ptr[node0 + t] = base;
    curs[t] = base;
  }
  if (b == NB - 1 && t == 0) row_ptr[N] = bend;
  __syncthreads();
  for (int i = bstart + t; i < bend; i += 256) {
    int pr = ebuf[i];
    int pos = atomicAdd(&curs[pr & 127], 1);
    col_src[pos] = pr >> 7;
  }
}

// -------------------- K5: single-pass softmax-aggregate (round-8 proven form) --------
// 64-lane group per node. Phase A: lane t=(edge e=t>>3, head hA=t&7) computes each
// (e,h) logit/exp exactly ONCE. Phase B: broadcast p and src via shfl; lane t
// accumulates d-pair t*2 (head hB=t>>3). 8 gathers in flight.
__global__ __launch_bounds__(256) void agg_kernel(const int* __restrict__ row_ptr,
    const int* __restrict__ col_src, const ushort* __restrict__ ft_bf,
    const float* __restrict__ a1, const float* __restrict__ a2,
    float* __restrict__ out) {
  const int node = blockIdx.x * 4 + (threadIdx.x >> 6);
  if (node >= N) return;
  const int t = threadIdx.x & 63;
  const int eSlot = t >> 3;
  const int hA = t & 7;
  const int hB = t >> 3;
  const int start = row_ptr[node], end = row_ptr[node + 1];
  const float a2nA = a2[node * 8 + hA];

  float l = 0.f, acc0 = 0.f, acc1 = 0.f;
  for (int base = start; base < end; base += 8) {
    int rem = end - base; rem = rem > 8 ? 8 : rem;
    int idx = base + (eSlot < rem ? eSlot : rem - 1);
    int s = col_src[idx];
    float lg = a1[s * 8 + hA] + a2nA;
    lg = lg > 0.f ? lg : ALPHA * lg;
    float p = (eSlot < rem) ? __expf(lg) : 0.f;
#pragma unroll
    for (int e = 0; e < 8; ++e) {
      float pe = __shfl(p, e * 8 + hB);
      int se = __shfl(s, e * 8);
      ushort2 f = *(const ushort2*)&ft_bf[se * 128 + t * 2];
      l += pe;
      acc0 = fmaf(pe, bf2f(f.x), acc0);
      acc1 = fmaf(pe, bf2f(f.y), acc1);
    }
  }
  float inv = (end > start) ? 1.f / l : 0.f;
  *(float2*)&out[node * 128 + t * 2] = make_float2(acc0 * inv, acc1 * inv);
}

// -------------------- launch --------------------
extern "C" void kernel_launch(void* const* d_in, const int* in_sizes, int n_in,
                              void* d_out, int out_size, void* d_ws, size_t ws_size,
                              hipStream_t stream) {
  const float* x      = (const float*)d_in[0];
  const float* W1     = (const float*)d_in[1];
  const float* W2     = (const float*)d_in[2];
  const float* attn_l = (const float*)d_in[3];
  const float* attn_r = (const float*)d_in[4];
  const int*   edge   = (const int*)d_in[5];
  const int*   src    = edge;
  const int*   dst    = edge + E;
  float* out = (float*)d_out;

  char* ws = (char*)d_ws;
  ushort* ft_bf       = (ushort*)(ws);                 // 12,800,000 B
  float*  a1          = (float*) (ws + 12800000);      //  1,600,000 B
  float*  a2          = (float*) (ws + 14400000);      //  1,600,000 B
  int*    row_ptr     = (int*)   (ws + 16000000);      //    200,064 B (N+1 ints)
  int*    bucket_base = (int*)   (ws + 16200064);      //      1,600 B (392 ints)
  int*    col_src     = (int*)   (ws + 16201664);      //  3,200,000 B
  ushort* wf1hi       = (ushort*)(ws + 19401664);      //     32,768 B each
  ushort* wf1lo       = (ushort*)(ws + 19434432);
  ushort* wf2hi       = (ushort*)(ws + 19467200);
  ushort* wf2lo       = (ushort*)(ws + 19499968);
  int*    ebuf        = (int*)   (ws + 19532736);      //  3,200,000 B
  int*    partial     = (int*)   (ws + 22732736);      //    307,328 B (196x392 ints)
  int*    chunk_base  = (int*)   (ws + 23040064);      //    307,328 B -> end ~23.35 MB

  k1_kernel<<<NBLK + 16, 256, 0, stream>>>(W1, W2, wf1hi, wf1lo, wf2hi, wf2lo, dst, partial);
  colscan_kernel<<<1, NBP, 0, stream>>>(partial, bucket_base, chunk_base);
  featpart_kernel<<<NBLK + FEATB, 256, SMEMB, stream>>>(
      x, wf1hi, wf1lo, wf2hi, wf2lo, attn_l, attn_r, ft_bf, a1, a2,
      src, dst, chunk_base, ebuf);
  fine_kernel<<<NB, 256, 0, stream>>>(ebuf, bucket_base, row_ptr, col_src);
  agg_kernel<<<(N + 3) / 4, 256, 0, stream>>>(row_ptr, col_src, ft_bf, a1, a2, out);
}

// Round 15
// 98.287 us; speedup vs baseline: 1.1289x; 1.1167x over previous
//
#include <hip/hip_runtime.h>

#define ALPHA 0.2f
constexpr int N = 50000;
constexpr int E = 800000;

typedef __attribute__((ext_vector_type(8))) short bf16x8;
typedef __attribute__((ext_vector_type(4))) float f32x4;

__device__ inline ushort f2bf(float v) {
  uint u = __float_as_uint(v);
  return (ushort)((u + 0x7fff + ((u >> 16) & 1)) >> 16);  // RNE, finite inputs
}
__device__ inline float bf2f(ushort u) { return __uint_as_float(((uint)u) << 16); }

constexpr int LDX = 136;  // LDS row stride in bf16: 272 B -> 4-bank/row rotation, 16B-aligned

constexpr int BN   = 128;                       // nodes per bucket
constexpr int NB   = (N + BN - 1) / BN;         // 391 buckets
constexpr int NBP  = 512;                       // padded for scans
constexpr int PSTR = 392;                       // partial row stride (ints)
constexpr int CHUNK = 4096;                     // edges per part/bhist block
constexpr int NBLK  = (E + CHUNK - 1) / CHUNK;  // 196
constexpr int FROWS = 32;                       // feat tile rows
constexpr int FEATB = (N + FROWS - 1) / FROWS;  // 1563 feat blocks
constexpr int SMEMB = 2 * FROWS * LDX * 2;      // 17408 B dynamic LDS

// -------------------- K1: bhist partials (blocks 0..195) + weight prep (196..211) ----
// frag slot f = (ks*8 + jb)*64 + l holds W[jb*16 + (l&15)][ks*32 + (l>>4)*8 + 0..7]
__global__ __launch_bounds__(256) void k1_kernel(const float* __restrict__ W1,
    const float* __restrict__ W2, ushort* __restrict__ wf1hi, ushort* __restrict__ wf1lo,
    ushort* __restrict__ wf2hi, ushort* __restrict__ wf2lo,
    const int* __restrict__ dst, int* __restrict__ partial) {
  const int bid = blockIdx.x;
  const int t = threadIdx.x;
  if (bid < NBLK) {
    __shared__ int lh[NB];
    const int e0 = bid * CHUNK, e1 = min(e0 + CHUNK, E);
    for (int i = t; i < NB; i += 256) lh[i] = 0;
    __syncthreads();
    for (int i = e0 + t; i < e1; i += 256)
      atomicAdd(&lh[((unsigned)dst[i]) >> 7], 1);
    __syncthreads();
    for (int i = t; i < NB; i += 256) partial[bid * PSTR + i] = lh[i];
    return;
  }
  int g = (bid - NBLK) * 256 + t;          // 0..4095
  const float* W = (g < 2048) ? W1 : W2;
  ushort* whi = (g < 2048) ? wf1hi : wf2hi;
  ushort* wlo = (g < 2048) ? wf1lo : wf2lo;
  int f = g & 2047;
  int ks = f >> 9, rem = f & 511, jb = rem >> 6, l = rem & 63;
  int m = jb * 16 + (l & 15), kb = ks * 32 + (l >> 4) * 8;
#pragma unroll
  for (int q = 0; q < 2; ++q) {
    float4 v = *(const float4*)&W[m * 128 + kb + q * 4];
    ushort4 hi, lo;
    hi.x = f2bf(v.x); lo.x = f2bf(v.x - bf2f(hi.x));
    hi.y = f2bf(v.y); lo.y = f2bf(v.y - bf2f(hi.y));
    hi.z = f2bf(v.z); lo.z = f2bf(v.z - bf2f(hi.z));
    hi.w = f2bf(v.w); lo.w = f2bf(v.w - bf2f(hi.w));
    *(ushort4*)&whi[f * 8 + q * 4] = hi;
    *(ushort4*)&wlo[f * 8 + q * 4] = lo;
  }
}

// -------------------- K2: column-sum + scan -> bucket_base, chunk_base ---------------
__global__ __launch_bounds__(NBP) void colscan_kernel(const int* __restrict__ partial,
    int* __restrict__ bucket_base, int* __restrict__ chunk_base) {
  __shared__ int sh[NBP];
  const int t = threadIdx.x;
  int tot = 0;
  if (t < NB)
    for (int blk = 0; blk < NBLK; ++blk) tot += partial[blk * PSTR + t];
  sh[t] = (t < NB) ? tot : 0;
  __syncthreads();
  for (int off = 1; off < NBP; off <<= 1) {
    int u = (t >= off) ? sh[t - off] : 0;
    __syncthreads();
    sh[t] += u;
    __syncthreads();
  }
  if (t < NB) {
    int base = sh[t] - tot;  // exclusive
    bucket_base[t] = base;
    int run = base;
    for (int blk = 0; blk < NBLK; ++blk) {
      chunk_base[blk * PSTR + t] = run;
      run += partial[blk * PSTR + t];
    }
  }
  if (t == NB - 1) bucket_base[NB] = sh[t];  // = E
}

// -------------------- K3: part (blocks 0..195) UNION feat (blocks 196..1758) ---------
__global__ __launch_bounds__(256, 6) void featpart_kernel(
    const float* __restrict__ x,
    const ushort* __restrict__ wf1hi, const ushort* __restrict__ wf1lo,
    const ushort* __restrict__ wf2hi, const ushort* __restrict__ wf2lo,
    const float* __restrict__ attn_l, const float* __restrict__ attn_r,
    ushort* __restrict__ ft_bf, float* __restrict__ a1, float* __restrict__ a2,
    const int* __restrict__ src, const int* __restrict__ dst,
    const int* __restrict__ chunk_base, int* __restrict__ ebuf) {
  extern __shared__ char smem[];
  const int bid = blockIdx.x;
  const int tid = threadIdx.x;

  if (bid < NBLK) {
    // ==== part: direct placement at precomputed per-(chunk,bucket) bases (no sort) ====
    int* curs = (int*)smem;          // [NB]
    const int e0 = bid * CHUNK, e1 = min(e0 + CHUNK, E);
    for (int k = tid; k < NB; k += 256) curs[k] = chunk_base[bid * PSTR + k];
    __syncthreads();
    for (int i = e0 + tid; i < e1; i += 256) {
      int s = src[i], d = dst[i];
      int pos = atomicAdd(&curs[((unsigned)d) >> 7], 1);
      ebuf[pos] = (s << 7) | (d & 127);
    }
    return;
  }

  // ======== feat: ft = lrelu(x@W1^T)@W2^T (bf16 hi/lo MFMA), a1/a2 reductions ========
  ushort* sXhi = (ushort*)smem;        // [FROWS][LDX]
  ushort* sXlo = sXhi + FROWS * LDX;
  const int w = tid >> 6, l = tid & 63;
  const int lr = l & 15, lg4 = l >> 4;
  const int rowBase = (bid - NBLK) * FROWS;

  for (int i = tid; i < FROWS * 32; i += 256) {
    int row = i >> 5, kc = i & 31;
    int g = rowBase + row;
    float4 v = make_float4(0.f, 0.f, 0.f, 0.f);
    if (g < N) v = reinterpret_cast<const float4*>(x)[g * 32 + kc];
    ushort4 hi, lo;
    hi.x = f2bf(v.x); lo.x = f2bf(v.x - bf2f(hi.x));
    hi.y = f2bf(v.y); lo.y = f2bf(v.y - bf2f(hi.y));
    hi.z = f2bf(v.z); lo.z = f2bf(v.z - bf2f(hi.z));
    hi.w = f2bf(v.w); lo.w = f2bf(v.w - bf2f(hi.w));
    *(ushort4*)&sXhi[row * LDX + kc * 4] = hi;
    *(ushort4*)&sXlo[row * LDX + kc * 4] = lo;
  }
  __syncthreads();

  f32x4 acc[2][2];
#pragma unroll
  for (int mi = 0; mi < 2; ++mi)
#pragma unroll
    for (int jj = 0; jj < 2; ++jj) acc[mi][jj] = (f32x4){0.f, 0.f, 0.f, 0.f};

  // ---- stage 1: h1 = x @ W1^T (B-frags streamed per ks from L2) ----
#pragma unroll
  for (int ks = 0; ks < 4; ++ks) {
    bf16x8 bh[2], bl[2], ah[2], al[2];
#pragma unroll
    for (int jj = 0; jj < 2; ++jj) {
      int off = ((ks * 8 + (2 * w + jj)) * 64 + l) * 8;
      bh[jj] = *(const bf16x8*)&wf1hi[off];
      bl[jj] = *(const bf16x8*)&wf1lo[off];
    }
#pragma unroll
    for (int mi = 0; mi < 2; ++mi) {
      int addr = (mi * 16 + lr) * LDX + ks * 32 + lg4 * 8;
      ah[mi] = *(const bf16x8*)&sXhi[addr];
      al[mi] = *(const bf16x8*)&sXlo[addr];
    }
#pragma unroll
    for (int mi = 0; mi < 2; ++mi)
#pragma unroll
      for (int jj = 0; jj < 2; ++jj) {
        acc[mi][jj] = __builtin_amdgcn_mfma_f32_16x16x32_bf16(ah[mi], bh[jj], acc[mi][jj], 0, 0, 0);
        acc[mi][jj] = __builtin_amdgcn_mfma_f32_16x16x32_bf16(ah[mi], bl[jj], acc[mi][jj], 0, 0, 0);
        acc[mi][jj] = __builtin_amdgcn_mfma_f32_16x16x32_bf16(al[mi], bh[jj], acc[mi][jj], 0, 0, 0);
      }
  }
  __syncthreads();  // all stage-1 LDS reads done before overwrite

  // write h2 = lrelu(h1) back to sX (hi/lo); D layout: row=4*(l>>4)+r, col=l&15
#pragma unroll
  for (int mi = 0; mi < 2; ++mi)
#pragma unroll
    for (int jj = 0; jj < 2; ++jj)
#pragma unroll
      for (int r = 0; r < 4; ++r) {
        float v = acc[mi][jj][r];
        v = v > 0.f ? v : ALPHA * v;
        int row = mi * 16 + lg4 * 4 + r;
        int col = w * 32 + jj * 16 + lr;
        ushort hv = f2bf(v);
        sXhi[row * LDX + col] = hv;
        sXlo[row * LDX + col] = f2bf(v - bf2f(hv));
      }
  __syncthreads();

#pragma unroll
  for (int mi = 0; mi < 2; ++mi)
#pragma unroll
    for (int jj = 0; jj < 2; ++jj) acc[mi][jj] = (f32x4){0.f, 0.f, 0.f, 0.f};

  // ---- stage 2: ft = h2 @ W2^T ----
#pragma unroll
  for (int ks = 0; ks < 4; ++ks) {
    bf16x8 bh[2], bl[2], ah[2], al[2];
#pragma unroll
    for (int jj = 0; jj < 2; ++jj) {
      int off = ((ks * 8 + (2 * w + jj)) * 64 + l) * 8;
      bh[jj] = *(const bf16x8*)&wf2hi[off];
      bl[jj] = *(const bf16x8*)&wf2lo[off];
    }
#pragma unroll
    for (int mi = 0; mi < 2; ++mi) {
      int addr = (mi * 16 + lr) * LDX + ks * 32 + lg4 * 8;
      ah[mi] = *(const bf16x8*)&sXhi[addr];
      al[mi] = *(const bf16x8*)&sXlo[addr];
    }
#pragma unroll
    for (int mi = 0; mi < 2; ++mi)
#pragma unroll
      for (int jj = 0; jj < 2; ++jj) {
        acc[mi][jj] = __builtin_amdgcn_mfma_f32_16x16x32_bf16(ah[mi], bh[jj], acc[mi][jj], 0, 0, 0);
        acc[mi][jj] = __builtin_amdgcn_mfma_f32_16x16x32_bf16(ah[mi], bl[jj], acc[mi][jj], 0, 0, 0);
        acc[mi][jj] = __builtin_amdgcn_mfma_f32_16x16x32_bf16(al[mi], bh[jj], acc[mi][jj], 0, 0, 0);
      }
  }

  // ---- epilogue: ft (bf16) + a1/a2 via 16-lane shuffle reduce over d ----
#pragma unroll
  for (int mi = 0; mi < 2; ++mi)
#pragma unroll
    for (int jj = 0; jj < 2; ++jj) {
      int h = 2 * w + jj;
      float alv = attn_l[h * 16 + lr], arv = attn_r[h * 16 + lr];
#pragma unroll
      for (int r = 0; r < 4; ++r) {
        float v = acc[mi][jj][r];
        int grow = rowBase + mi * 16 + lg4 * 4 + r;
        bool valid = grow < N;
        if (valid) ft_bf[grow * 128 + h * 16 + lr] = f2bf(v);
        float sl = v * alv, sr = v * arv;
#pragma unroll
        for (int off = 8; off; off >>= 1) {
          sl += __shfl_xor(sl, off, 16);
          sr += __shfl_xor(sr, off, 16);
        }
        if (valid && lr == 0) { a1[grow * 8 + h] = sl; a2[grow * 8 + h] = sr; }
      }
    }
}

// ---- K4: per-bucket fine sort + local CSR build (row_ptr derived here) --------------
__global__ __launch_bounds__(256) void fine_kernel(const int* __restrict__ ebuf,
    const int* __restrict__ bucket_base, int* __restrict__ row_ptr,
    int* __restrict__ col_src) {
  __shared__ int ldeg[BN], sc[BN], curs[BN];
  const int b = blockIdx.x, t = threadIdx.x;
  const int node0 = b * BN;
  const int nloc = min(BN, N - node0);
  const int bstart = bucket_base[b], bend = bucket_base[b + 1];
  if (t < BN) ldeg[t] = 0;
  __syncthreads();
  for (int i = bstart + t; i < bend; i += 256)
    atomicAdd(&ldeg[ebuf[i] & 127], 1);
  __syncthreads();
  if (t < BN) sc[t] = ldeg[t];
  __syncthreads();
#pragma unroll
  for (int off = 1; off < BN; off <<= 1) {
    int u = (t < BN && t >= off) ? sc[t - off] : 0;
    __syncthreads();
    if (t < BN) sc[t] += u;
    __syncthreads();
  }
  if (t < nloc) {
    int base = bstart + sc[t] - ldeg[t];
    row_ptr[node0 + t] = base;
    curs[t] = base;
  }
  if (b == NB - 1 && t == 0) row_ptr[N] = bend;
  __syncthreads();
  for (int i = bstart + t; i < bend; i += 256) {
    int pr = ebuf[i];
    int pos = atomicAdd(&curs[pr & 127], 1);
    col_src[pos] = pr >> 7;
  }
}

// -------------------- K5: single-pass softmax-aggregate ------------------------------
// 64-lane group per node. Phase A: lane t=(edge e=t>>3, head hA=t&7) computes each
// (e,h) logit/exp exactly ONCE. Phase B: broadcast p and src via shfl; lane t
// accumulates d-pair t*2 (head hB=t>>3). 8 gathers in flight.
__global__ __launch_bounds__(256) void agg_kernel(const int* __restrict__ row_ptr,
    const int* __restrict__ col_src, const ushort* __restrict__ ft_bf,
    const float* __restrict__ a1, const float* __restrict__ a2,
    float* __restrict__ out) {
  const int node = blockIdx.x * 4 + (threadIdx.x >> 6);
  if (node >= N) return;
  const int t = threadIdx.x & 63;
  const int eSlot = t >> 3;
  const int hA = t & 7;
  const int hB = t >> 3;
  const int start = row_ptr[node], end = row_ptr[node + 1];
  const float a2nA = a2[node * 8 + hA];

  float l = 0.f, acc0 = 0.f, acc1 = 0.f;
  for (int base = start; base < end; base += 8) {
    int rem = end - base; rem = rem > 8 ? 8 : rem;
    int idx = base + (eSlot < rem ? eSlot : rem - 1);
    int s = col_src[idx];
    float lg = a1[s * 8 + hA] + a2nA;
    lg = lg > 0.f ? lg : ALPHA * lg;
    float p = (eSlot < rem) ? __expf(lg) : 0.f;
#pragma unroll
    for (int e = 0; e < 8; ++e) {
      float pe = __shfl(p, e * 8 + hB);
      int se = __shfl(s, e * 8);
      ushort2 f = *(const ushort2*)&ft_bf[se * 128 + t * 2];
      l += pe;
      acc0 = fmaf(pe, bf2f(f.x), acc0);
      acc1 = fmaf(pe, bf2f(f.y), acc1);
    }
  }
  float inv = (end > start) ? 1.f / l : 0.f;
  *(float2*)&out[node * 128 + t * 2] = make_float2(acc0 * inv, acc1 * inv);
}

// -------------------- launch --------------------
extern "C" void kernel_launch(void* const* d_in, const int* in_sizes, int n_in,
                              void* d_out, int out_size, void* d_ws, size_t ws_size,
                              hipStream_t stream) {
  const float* x      = (const float*)d_in[0];
  const float* W1     = (const float*)d_in[1];
  const float* W2     = (const float*)d_in[2];
  const float* attn_l = (const float*)d_in[3];
  const float* attn_r = (const float*)d_in[4];
  const int*   edge   = (const int*)d_in[5];
  const int*   src    = edge;
  const int*   dst    = edge + E;
  float* out = (float*)d_out;

  char* ws = (char*)d_ws;
  ushort* ft_bf       = (ushort*)(ws);                 // 12,800,000 B
  float*  a1          = (float*) (ws + 12800000);      //  1,600,000 B
  float*  a2          = (float*) (ws + 14400000);      //  1,600,000 B
  int*    row_ptr     = (int*)   (ws + 16000000);      //    200,064 B (N+1 ints)
  int*    bucket_base = (int*)   (ws + 16200064);      //      1,600 B (392 ints)
  int*    col_src     = (int*)   (ws + 16201664);      //  3,200,000 B
  ushort* wf1hi       = (ushort*)(ws + 19401664);      //     32,768 B each
  ushort* wf1lo       = (ushort*)(ws + 19434432);
  ushort* wf2hi       = (ushort*)(ws + 19467200);
  ushort* wf2lo       = (ushort*)(ws + 19499968);
  int*    ebuf        = (int*)   (ws + 19532736);      //  3,200,000 B
  int*    partial     = (int*)   (ws + 22732736);      //    307,328 B (196x392 ints)
  int*    chunk_base  = (int*)   (ws + 23040064);      //    307,328 B -> end ~23.35 MB

  k1_kernel<<<NBLK + 16, 256, 0, stream>>>(W1, W2, wf1hi, wf1lo, wf2hi, wf2lo, dst, partial);
  colscan_kernel<<<1, NBP, 0, stream>>>(partial, bucket_base, chunk_base);
  featpart_kernel<<<NBLK + FEATB, 256, SMEMB, stream>>>(
      x, wf1hi, wf1lo, wf2hi, wf2lo, attn_l, attn_r, ft_bf, a1, a2,
      src, dst, chunk_base, ebuf);
  fine_kernel<<<NB, 256, 0, stream>>>(ebuf, bucket_base, row_ptr, col_src);
  agg_kernel<<<(N + 3) / 4, 256, 0, stream>>>(row_ptr, col_src, ft_bf, a1, a2, out);
}

// Round 16
// 90.094 us; speedup vs baseline: 1.2316x; 1.0909x over previous
//
#include <hip/hip_runtime.h>

#define ALPHA 0.2f
constexpr int N = 50000;
constexpr int E = 800000;

typedef __attribute__((ext_vector_type(8))) short bf16x8;
typedef __attribute__((ext_vector_type(4))) float f32x4;

__device__ inline ushort f2bf(float v) {
  uint u = __float_as_uint(v);
  return (ushort)((u + 0x7fff + ((u >> 16) & 1)) >> 16);  // RNE, finite inputs
}
__device__ inline float bf2f(ushort u) { return __uint_as_float(((uint)u) << 16); }

constexpr int LDX = 136;  // LDS row stride in bf16: 272 B -> 4-bank/row rotation, 16B-aligned

constexpr int BN   = 128;                       // nodes per bucket
constexpr int NB   = (N + BN - 1) / BN;         // 391 buckets
constexpr int NBP  = 512;                       // padded for bucket scan
constexpr int CHUNK = 4096;                     // edges per part/bhist block
constexpr int NBLK  = (E + CHUNK - 1) / CHUNK;  // 196
constexpr int CSTR  = 200;                      // chunk stride in transposed partials
constexpr int FROWS = 32;                       // feat tile rows
constexpr int FEATB = (N + FROWS - 1) / FROWS;  // 1563 feat blocks
constexpr int SMEMB = 2 * FROWS * LDX * 2;      // 17408 B dynamic LDS

// -------------------- K1: bhist partials (blocks 0..195) + weight prep (196..211) ----
// partialT is TRANSPOSED: [bucket][chunk] so colscanA reads coalesced rows.
// frag slot f = (ks*8 + jb)*64 + l holds W[jb*16 + (l&15)][ks*32 + (l>>4)*8 + 0..7]
__global__ __launch_bounds__(256) void k1_kernel(const float* __restrict__ W1,
    const float* __restrict__ W2, ushort* __restrict__ wf1hi, ushort* __restrict__ wf1lo,
    ushort* __restrict__ wf2hi, ushort* __restrict__ wf2lo,
    const int* __restrict__ dst, int* __restrict__ partialT) {
  const int bid = blockIdx.x;
  const int t = threadIdx.x;
  if (bid < NBLK) {
    __shared__ int lh[NB];
    const int e0 = bid * CHUNK, e1 = min(e0 + CHUNK, E);
    for (int i = t; i < NB; i += 256) lh[i] = 0;
    __syncthreads();
    for (int i = e0 + t; i < e1; i += 256)
      atomicAdd(&lh[((unsigned)dst[i]) >> 7], 1);
    __syncthreads();
    for (int i = t; i < NB; i += 256) partialT[i * CSTR + bid] = lh[i];
    return;
  }
  int g = (bid - NBLK) * 256 + t;          // 0..4095
  const float* W = (g < 2048) ? W1 : W2;
  ushort* whi = (g < 2048) ? wf1hi : wf2hi;
  ushort* wlo = (g < 2048) ? wf1lo : wf2lo;
  int f = g & 2047;
  int ks = f >> 9, rem = f & 511, jb = rem >> 6, l = rem & 63;
  int m = jb * 16 + (l & 15), kb = ks * 32 + (l >> 4) * 8;
#pragma unroll
  for (int q = 0; q < 2; ++q) {
    float4 v = *(const float4*)&W[m * 128 + kb + q * 4];
    ushort4 hi, lo;
    hi.x = f2bf(v.x); lo.x = f2bf(v.x - bf2f(hi.x));
    hi.y = f2bf(v.y); lo.y = f2bf(v.y - bf2f(hi.y));
    hi.z = f2bf(v.z); lo.z = f2bf(v.z - bf2f(hi.z));
    hi.w = f2bf(v.w); lo.w = f2bf(v.w - bf2f(hi.w));
    *(ushort4*)&whi[f * 8 + q * 4] = hi;
    *(ushort4*)&wlo[f * 8 + q * 4] = lo;
  }
}

// -------------------- K2a: per-bucket scan over chunks (391 parallel blocks) ---------
__global__ __launch_bounds__(256) void colscanA_kernel(const int* __restrict__ partialT,
    int* __restrict__ chunkrel, int* __restrict__ btot) {
  __shared__ int sh[256];
  const int b = blockIdx.x, t = threadIdx.x;
  int v = (t < NBLK) ? partialT[b * CSTR + t] : 0;
  sh[t] = v;
  __syncthreads();
  for (int off = 1; off < 256; off <<= 1) {
    int u = (t >= off) ? sh[t - off] : 0;
    __syncthreads();
    sh[t] += u;
    __syncthreads();
  }
  if (t < NBLK) chunkrel[b * CSTR + t] = sh[t] - v;  // exclusive within bucket
  if (t == 255) btot[b] = sh[255];                   // bucket total
}

// -------------------- K2b: scan of 391 bucket totals -> bucket_base ------------------
__global__ __launch_bounds__(NBP) void colscanB_kernel(const int* __restrict__ btot,
    int* __restrict__ bucket_base) {
  __shared__ int sh[NBP];
  const int t = threadIdx.x;
  int v = (t < NB) ? btot[t] : 0;
  sh[t] = v;
  __syncthreads();
  for (int off = 1; off < NBP; off <<= 1) {
    int u = (t >= off) ? sh[t - off] : 0;
    __syncthreads();
    sh[t] += u;
    __syncthreads();
  }
  if (t < NB) bucket_base[t] = sh[t] - v;  // exclusive
  if (t == NB - 1) bucket_base[NB] = sh[t];  // = E
}

// -------------------- K3: part (blocks 0..195) UNION feat (blocks 196..1758) ---------
__global__ __launch_bounds__(256, 6) void featpart_kernel(
    const float* __restrict__ x,
    const ushort* __restrict__ wf1hi, const ushort* __restrict__ wf1lo,
    const ushort* __restrict__ wf2hi, const ushort* __restrict__ wf2lo,
    const float* __restrict__ attn_l, const float* __restrict__ attn_r,
    ushort* __restrict__ ft_bf, float* __restrict__ a1, float* __restrict__ a2,
    const int* __restrict__ src, const int* __restrict__ dst,
    const int* __restrict__ bucket_base, const int* __restrict__ chunkrel,
    int* __restrict__ ebuf) {
  extern __shared__ char smem[];
  const int bid = blockIdx.x;
  const int tid = threadIdx.x;

  if (bid < NBLK) {
    // ==== part: direct placement at bucket_base + within-bucket chunk prefix ====
    int* curs = (int*)smem;          // [NB]
    const int e0 = bid * CHUNK, e1 = min(e0 + CHUNK, E);
    for (int k = tid; k < NB; k += 256)
      curs[k] = bucket_base[k] + chunkrel[k * CSTR + bid];
    __syncthreads();
    for (int i = e0 + tid; i < e1; i += 256) {
      int s = src[i], d = dst[i];
      int pos = atomicAdd(&curs[((unsigned)d) >> 7], 1);
      ebuf[pos] = (s << 7) | (d & 127);
    }
    return;
  }

  // ======== feat: ft = lrelu(x@W1^T)@W2^T (bf16 hi/lo MFMA), a1/a2 reductions ========
  ushort* sXhi = (ushort*)smem;        // [FROWS][LDX]
  ushort* sXlo = sXhi + FROWS * LDX;
  const int w = tid >> 6, l = tid & 63;
  const int lr = l & 15, lg4 = l >> 4;
  const int rowBase = (bid - NBLK) * FROWS;

  for (int i = tid; i < FROWS * 32; i += 256) {
    int row = i >> 5, kc = i & 31;
    int g = rowBase + row;
    float4 v = make_float4(0.f, 0.f, 0.f, 0.f);
    if (g < N) v = reinterpret_cast<const float4*>(x)[g * 32 + kc];
    ushort4 hi, lo;
    hi.x = f2bf(v.x); lo.x = f2bf(v.x - bf2f(hi.x));
    hi.y = f2bf(v.y); lo.y = f2bf(v.y - bf2f(hi.y));
    hi.z = f2bf(v.z); lo.z = f2bf(v.z - bf2f(hi.z));
    hi.w = f2bf(v.w); lo.w = f2bf(v.w - bf2f(hi.w));
    *(ushort4*)&sXhi[row * LDX + kc * 4] = hi;
    *(ushort4*)&sXlo[row * LDX + kc * 4] = lo;
  }
  __syncthreads();

  f32x4 acc[2][2];
#pragma unroll
  for (int mi = 0; mi < 2; ++mi)
#pragma unroll
    for (int jj = 0; jj < 2; ++jj) acc[mi][jj] = (f32x4){0.f, 0.f, 0.f, 0.f};

  // ---- stage 1: h1 = x @ W1^T (B-frags streamed per ks from L2) ----
#pragma unroll
  for (int ks = 0; ks < 4; ++ks) {
    bf16x8 bh[2], bl[2], ah[2], al[2];
#pragma unroll
    for (int jj = 0; jj < 2; ++jj) {
      int off = ((ks * 8 + (2 * w + jj)) * 64 + l) * 8;
      bh[jj] = *(const bf16x8*)&wf1hi[off];
      bl[jj] = *(const bf16x8*)&wf1lo[off];
    }
#pragma unroll
    for (int mi = 0; mi < 2; ++mi) {
      int addr = (mi * 16 + lr) * LDX + ks * 32 + lg4 * 8;
      ah[mi] = *(const bf16x8*)&sXhi[addr];
      al[mi] = *(const bf16x8*)&sXlo[addr];
    }
#pragma unroll
    for (int mi = 0; mi < 2; ++mi)
#pragma unroll
      for (int jj = 0; jj < 2; ++jj) {
        acc[mi][jj] = __builtin_amdgcn_mfma_f32_16x16x32_bf16(ah[mi], bh[jj], acc[mi][jj], 0, 0, 0);
        acc[mi][jj] = __builtin_amdgcn_mfma_f32_16x16x32_bf16(ah[mi], bl[jj], acc[mi][jj], 0, 0, 0);
        acc[mi][jj] = __builtin_amdgcn_mfma_f32_16x16x32_bf16(al[mi], bh[jj], acc[mi][jj], 0, 0, 0);
      }
  }
  __syncthreads();  // all stage-1 LDS reads done before overwrite

  // write h2 = lrelu(h1) back to sX (hi/lo); D layout: row=4*(l>>4)+r, col=l&15
#pragma unroll
  for (int mi = 0; mi < 2; ++mi)
#pragma unroll
    for (int jj = 0; jj < 2; ++jj)
#pragma unroll
      for (int r = 0; r < 4; ++r) {
        float v = acc[mi][jj][r];
        v = v > 0.f ? v : ALPHA * v;
        int row = mi * 16 + lg4 * 4 + r;
        int col = w * 32 + jj * 16 + lr;
        ushort hv = f2bf(v);
        sXhi[row * LDX + col] = hv;
        sXlo[row * LDX + col] = f2bf(v - bf2f(hv));
      }
  __syncthreads();

#pragma unroll
  for (int mi = 0; mi < 2; ++mi)
#pragma unroll
    for (int jj = 0; jj < 2; ++jj) acc[mi][jj] = (f32x4){0.f, 0.f, 0.f, 0.f};

  // ---- stage 2: ft = h2 @ W2^T ----
#pragma unroll
  for (int ks = 0; ks < 4; ++ks) {
    bf16x8 bh[2], bl[2], ah[2], al[2];
#pragma unroll
    for (int jj = 0; jj < 2; ++jj) {
      int off = ((ks * 8 + (2 * w + jj)) * 64 + l) * 8;
      bh[jj] = *(const bf16x8*)&wf2hi[off];
      bl[jj] = *(const bf16x8*)&wf2lo[off];
    }
#pragma unroll
    for (int mi = 0; mi < 2; ++mi) {
      int addr = (mi * 16 + lr) * LDX + ks * 32 + lg4 * 8;
      ah[mi] = *(const bf16x8*)&sXhi[addr];
      al[mi] = *(const bf16x8*)&sXlo[addr];
    }
#pragma unroll
    for (int mi = 0; mi < 2; ++mi)
#pragma unroll
      for (int jj = 0; jj < 2; ++jj) {
        acc[mi][jj] = __builtin_amdgcn_mfma_f32_16x16x32_bf16(ah[mi], bh[jj], acc[mi][jj], 0, 0, 0);
        acc[mi][jj] = __builtin_amdgcn_mfma_f32_16x16x32_bf16(ah[mi], bl[jj], acc[mi][jj], 0, 0, 0);
        acc[mi][jj] = __builtin_amdgcn_mfma_f32_16x16x32_bf16(al[mi], bh[jj], acc[mi][jj], 0, 0, 0);
      }
  }

  // ---- epilogue: ft (bf16) + a1/a2 via 16-lane shuffle reduce over d ----
#pragma unroll
  for (int mi = 0; mi < 2; ++mi)
#pragma unroll
    for (int jj = 0; jj < 2; ++jj) {
      int h = 2 * w + jj;
      float alv = attn_l[h * 16 + lr], arv = attn_r[h * 16 + lr];
#pragma unroll
      for (int r = 0; r < 4; ++r) {
        float v = acc[mi][jj][r];
        int grow = rowBase + mi * 16 + lg4 * 4 + r;
        bool valid = grow < N;
        if (valid) ft_bf[grow * 128 + h * 16 + lr] = f2bf(v);
        float sl = v * alv, sr = v * arv;
#pragma unroll
        for (int off = 8; off; off >>= 1) {
          sl += __shfl_xor(sl, off, 16);
          sr += __shfl_xor(sr, off, 16);
        }
        if (valid && lr == 0) { a1[grow * 8 + h] = sl; a2[grow * 8 + h] = sr; }
      }
    }
}

// ---- K4: per-bucket fine sort + local CSR build (row_ptr derived here) --------------
__global__ __launch_bounds__(256) void fine_kernel(const int* __restrict__ ebuf,
    const int* __restrict__ bucket_base, int* __restrict__ row_ptr,
    int* __restrict__ col_src) {
  __shared__ int ldeg[BN], sc[BN], curs[BN];
  const int b = blockIdx.x, t = threadIdx.x;
  const int node0 = b * BN;
  const int nloc = min(BN, N - node0);
  const int bstart = bucket_base[b], bend = bucket_base[b + 1];
  if (t < BN) ldeg[t] = 0;
  __syncthreads();
  for (int i = bstart + t; i < bend; i += 256)
    atomicAdd(&ldeg[ebuf[i] & 127], 1);
  __syncthreads();
  if (t < BN) sc[t] = ldeg[t];
  __syncthreads();
#pragma unroll
  for (int off = 1; off < BN; off <<= 1) {
    int u = (t < BN && t >= off) ? sc[t - off] : 0;
    __syncthreads();
    if (t < BN) sc[t] += u;
    __syncthreads();
  }
  if (t < nloc) {
    int base = bstart + sc[t] - ldeg[t];
    row_ptr[node0 + t] = base;
    curs[t] = base;
  }
  if (b == NB - 1 && t == 0) row_ptr[N] = bend;
  __syncthreads();
  for (int i = bstart + t; i < bend; i += 256) {
    int pr = ebuf[i];
    int pos = atomicAdd(&curs[pr & 127], 1);
    col_src[pos] = pr >> 7;
  }
}

// -------------------- K5: single-pass softmax-aggregate ------------------------------
// 64-lane group per node. Phase A: lane t=(edge e=t>>3, head hA=t&7) computes each
// (e,h) logit/exp exactly ONCE. Phase B: broadcast p and src via shfl; lane t
// accumulates d-pair t*2 (head hB=t>>3). 8 gathers in flight.
__global__ __launch_bounds__(256) void agg_kernel(const int* __restrict__ row_ptr,
    const int* __restrict__ col_src, const ushort* __restrict__ ft_bf,
    const float* __restrict__ a1, const float* __restrict__ a2,
    float* __restrict__ out) {
  const int node = blockIdx.x * 4 + (threadIdx.x >> 6);
  if (node >= N) return;
  const int t = threadIdx.x & 63;
  const int eSlot = t >> 3;
  const int hA = t & 7;
  const int hB = t >> 3;
  const int start = row_ptr[node], end = row_ptr[node + 1];
  const float a2nA = a2[node * 8 + hA];

  float l = 0.f, acc0 = 0.f, acc1 = 0.f;
  for (int base = start; base < end; base += 8) {
    int rem = end - base; rem = rem > 8 ? 8 : rem;
    int idx = base + (eSlot < rem ? eSlot : rem - 1);
    int s = col_src[idx];
    float lg = a1[s * 8 + hA] + a2nA;
    lg = lg > 0.f ? lg : ALPHA * lg;
    float p = (eSlot < rem) ? __expf(lg) : 0.f;
#pragma unroll
    for (int e = 0; e < 8; ++e) {
      float pe = __shfl(p, e * 8 + hB);
      int se = __shfl(s, e * 8);
      ushort2 f = *(const ushort2*)&ft_bf[se * 128 + t * 2];
      l += pe;
      acc0 = fmaf(pe, bf2f(f.x), acc0);
      acc1 = fmaf(pe, bf2f(f.y), acc1);
    }
  }
  float inv = (end > start) ? 1.f / l : 0.f;
  *(float2*)&out[node * 128 + t * 2] = make_float2(acc0 * inv, acc1 * inv);
}

// -------------------- launch --------------------
extern "C" void kernel_launch(void* const* d_in, const int* in_sizes, int n_in,
                              void* d_out, int out_size, void* d_ws, size_t ws_size,
                              hipStream_t stream) {
  const float* x      = (const float*)d_in[0];
  const float* W1     = (const float*)d_in[1];
  const float* W2     = (const float*)d_in[2];
  const float* attn_l = (const float*)d_in[3];
  const float* attn_r = (const float*)d_in[4];
  const int*   edge   = (const int*)d_in[5];
  const int*   src    = edge;
  const int*   dst    = edge + E;
  float* out = (float*)d_out;

  char* ws = (char*)d_ws;
  ushort* ft_bf       = (ushort*)(ws);                 // 12,800,000 B
  float*  a1          = (float*) (ws + 12800000);      //  1,600,000 B
  float*  a2          = (float*) (ws + 14400000);      //  1,600,000 B
  int*    row_ptr     = (int*)   (ws + 16000000);      //    200,064 B (N+1 ints)
  int*    bucket_base = (int*)   (ws + 16200064);      //      1,600 B (392 ints)
  int*    col_src     = (int*)   (ws + 16201664);      //  3,200,000 B
  ushort* wf1hi       = (ushort*)(ws + 19401664);      //     32,768 B each
  ushort* wf1lo       = (ushort*)(ws + 19434432);
  ushort* wf2hi       = (ushort*)(ws + 19467200);
  ushort* wf2lo       = (ushort*)(ws + 19499968);
  int*    ebuf        = (int*)   (ws + 19532736);      //  3,200,000 B
  int*    partialT    = (int*)   (ws + 22732736);      //    312,800 B (391x200 ints)
  int*    chunkrel    = (int*)   (ws + 23045536);      //    312,800 B
  int*    btot        = (int*)   (ws + 23358336);      //      1,600 B -> end ~23.36 MB

  k1_kernel<<<NBLK + 16, 256, 0, stream>>>(W1, W2, wf1hi, wf1lo, wf2hi, wf2lo, dst, partialT);
  colscanA_kernel<<<NB, 256, 0, stream>>>(partialT, chunkrel, btot);
  colscanB_kernel<<<1, NBP, 0, stream>>>(btot, bucket_base);
  featpart_kernel<<<NBLK + FEATB, 256, SMEMB, stream>>>(
      x, wf1hi, wf1lo, wf2hi, wf2lo, attn_l, attn_r, ft_bf, a1, a2,
      src, dst, bucket_base, chunkrel, ebuf);
  fine_kernel<<<NB, 256, 0, stream>>>(ebuf, bucket_base, row_ptr, col_src);
  agg_kernel<<<(N + 3) / 4, 256, 0, stream>>>(row_ptr, col_src, ft_bf, a1, a2, out);
}